// Round 8
// baseline (237.292 us; speedup 1.0000x reference)
//
#include <hip/hip_runtime.h>
#include <hip/hip_bf16.h>

#define NPAIR 4096
#define DIM   768
#define N2    8192
#define BM    128            // block rows (4 waves as 2x2, each 64x64)
#define BNB   128            // block cols per col-block
#define KBLK  32             // K tile (4 octets of 8 bf16) -> 16KB/tile, dbuf=32KB
#define KITER (DIM / KBLK)   // 24
#define NSTRIP 16            // grid.y
#define CPB   ((N2 / BNB) / NSTRIP)    // 4 col-blocks per strip
#define NBI   (N2 / BM)      // 64
#define TOTIT (CPB * KITER)  // 96

constexpr float INV_T = 1.0f / 0.07f;  // also the fixed softmax max M

typedef __bf16 bf16x8 __attribute__((ext_vector_type(8)));
typedef float  f32x16 __attribute__((ext_vector_type(16)));

__device__ inline unsigned short f2bf(float x) {
    return __builtin_bit_cast(unsigned short, (__bf16)x);
}

// ---------------- normalize: one wave per row, fp32 in -> bf16 out ----------
__global__ void knorm(const float* __restrict__ z1, const float* __restrict__ z2,
                      unsigned short* __restrict__ zb) {
    const int row  = blockIdx.x * 4 + (threadIdx.x >> 6);
    const int lane = threadIdx.x & 63;
    const float* src = (row < NPAIR) ? (z1 + (size_t)row * DIM)
                                     : (z2 + (size_t)(row - NPAIR) * DIM);
    float4 v[3];
    float ss = 0.f;
#pragma unroll
    for (int i = 0; i < 3; ++i) {
        v[i] = reinterpret_cast<const float4*>(src)[lane + 64 * i];
        ss += v[i].x * v[i].x + v[i].y * v[i].y + v[i].z * v[i].z + v[i].w * v[i].w;
    }
#pragma unroll
    for (int off = 32; off; off >>= 1) ss += __shfl_xor(ss, off);
    const float scale = 1.0f / fmaxf(sqrtf(ss), 1e-12f);
    ushort4* dst = reinterpret_cast<ushort4*>(zb + (size_t)row * DIM);
#pragma unroll
    for (int i = 0; i < 3; ++i) {
        ushort4 o;
        o.x = f2bf(v[i].x * scale); o.y = f2bf(v[i].y * scale);
        o.z = f2bf(v[i].z * scale); o.w = f2bf(v[i].w * scale);
        dst[lane + 64 * i] = o;
    }
}

// ---------------- positive-pair dots: one wave per pair ---------------------
__global__ void kpos(const unsigned short* __restrict__ zb, float* __restrict__ pos) {
    const int pair = blockIdx.x * 4 + (threadIdx.x >> 6);
    const int lane = threadIdx.x & 63;
    const bf16x8* a = reinterpret_cast<const bf16x8*>(zb + (size_t)pair * DIM);
    const bf16x8* b = reinterpret_cast<const bf16x8*>(zb + (size_t)(pair + NPAIR) * DIM);
    float s = 0.f;
#pragma unroll
    for (int c = 0; c < 2; ++c) {
        const int idx = lane + 64 * c;
        if (idx < 96) {
            bf16x8 va = a[idx], vb = b[idx];
#pragma unroll
            for (int j = 0; j < 8; ++j) s += (float)va[j] * (float)vb[j];
        }
    }
#pragma unroll
    for (int off = 32; off; off >>= 1) s += __shfl_xor(s, off);
    if (lane == 0) pos[pair] = s * INV_T;
}

// ---------------- main: full sweep, counted-vmcnt double-buffer -------------
// R3 engine (128x128 block, wave 64x64 via 2x2 of mfma_f32_32x32x16_bf16,
// grid 64x16, 4 blocks/CU) + KBLK=32 double-buffer: next K-tile's 4
// global_load_lds stay in flight across barriers (s_waitcnt vmcnt(4)).
// LDS stays 32KB -> occupancy unchanged vs R3 (the R4 mistake avoided).
__global__ __launch_bounds__(256) void klse(const unsigned short* __restrict__ zb,
                                            float* __restrict__ rowsum) {
    __shared__ __align__(16) unsigned short As[2][BM * KBLK];   // 2 x 8 KB
    __shared__ __align__(16) unsigned short Bs[2][BM * KBLK];   // 2 x 8 KB
    const int tid  = threadIdx.x;
    const int wave = tid >> 6;
    const int lane = tid & 63;
    const int wr = wave >> 1, wc = wave & 1;
    const int hi = lane >> 5, rlo = lane & 31;
    const int bi = blockIdx.x;
    const int rb = bi * BM;

    const int xr  = (rlo >> 1) & 3;               // read-side slot swizzle
    const int raA = (wr * 64 + rlo) * KBLK;
    const int raB = raA + 32 * KBLK;
    const int caA = (wc * 64 + rlo) * KBLK;
    const int caB = caA + 32 * KBLK;

    // stage K-tile (ct,kt) into buffer buf: 1024 granules of 16B, 4/thread
    auto stage = [&](int ct, int kt, int buf) {
        const int c0 = (blockIdx.y * CPB + ct) * BNB;
#pragma unroll
        for (int i = 0; i < 2; ++i) {
            const int g = i * 256 + tid;           // granule in [0,512)
            const int r = g >> 2, slot = g & 3;
            const int ksrc = kt * KBLK + ((slot ^ ((r >> 1) & 3)) << 3);
            const unsigned short* srcA = zb + (size_t)(rb + r) * DIM + ksrc;
            const unsigned short* srcB = zb + (size_t)(c0 + r) * DIM + ksrc;
            __builtin_amdgcn_global_load_lds(
                (const __attribute__((address_space(1))) unsigned int*)srcA,
                (__attribute__((address_space(3))) unsigned int*)(&As[buf][g * 8]),
                16, 0, 0);
            __builtin_amdgcn_global_load_lds(
                (const __attribute__((address_space(1))) unsigned int*)srcB,
                (__attribute__((address_space(3))) unsigned int*)(&Bs[buf][g * 8]),
                16, 0, 0);
        }
    };

    f32x16 acc00 = {}, acc01 = {}, acc10 = {}, acc11 = {};

    stage(0, 0, 0);
    int ct = 0, kt = 0;
    for (int it = 0; it < TOTIT; ++it) {
        const int cur = it & 1;
        int nct = ct, nkt = kt + 1;
        if (nkt == KITER) { nkt = 0; ++nct; }
        if (it + 1 < TOTIT) {
            stage(nct, nkt, cur ^ 1);                         // prefetch next
            asm volatile("s_waitcnt vmcnt(4)" ::: "memory");  // cur tile landed
        } else {
            asm volatile("s_waitcnt vmcnt(0)" ::: "memory");
        }
        __builtin_amdgcn_s_barrier();
        asm volatile("" ::: "memory");
#pragma unroll
        for (int tt = 0; tt < 2; ++tt) {
            const int ko = tt * 2 + hi;
            const int so = (ko ^ xr) << 3;         // swizzled octet offset
            bf16x8 a0 = *reinterpret_cast<const bf16x8*>(&As[cur][raA + so]);
            bf16x8 a1 = *reinterpret_cast<const bf16x8*>(&As[cur][raB + so]);
            bf16x8 b0 = *reinterpret_cast<const bf16x8*>(&Bs[cur][caA + so]);
            bf16x8 b1 = *reinterpret_cast<const bf16x8*>(&Bs[cur][caB + so]);
            acc00 = __builtin_amdgcn_mfma_f32_32x32x16_bf16(a0, b0, acc00, 0, 0, 0);
            acc01 = __builtin_amdgcn_mfma_f32_32x32x16_bf16(a0, b1, acc01, 0, 0, 0);
            acc10 = __builtin_amdgcn_mfma_f32_32x32x16_bf16(a1, b0, acc10, 0, 0, 0);
            acc11 = __builtin_amdgcn_mfma_f32_32x32x16_bf16(a1, b1, acc11, 0, 0, 0);
        }
        asm volatile("" ::: "memory");
        __builtin_amdgcn_s_barrier();   // reads done before next stage overwrites

        if (kt == KITER - 1) {
            // ---------- epilogue for col-block ct: exp, mask, reduce --------
            const int cblk = blockIdx.y * CPB + ct;
            const bool on_diag = (cblk == bi);
            const int row0b = rb + wr * 64 + 4 * hi;
            const int colg  = cblk * BNB + wc * 64 + rlo;
            float ps0[16], ps1[16];
#pragma unroll
            for (int r = 0; r < 16; ++r) {
                const int rg0 = row0b + (r & 3) + 8 * (r >> 2);
                float e00 = __expf((acc00[r] - 1.0f) * INV_T);
                float e01 = __expf((acc01[r] - 1.0f) * INV_T);
                float e10 = __expf((acc10[r] - 1.0f) * INV_T);
                float e11 = __expf((acc11[r] - 1.0f) * INV_T);
                if (on_diag) {
                    if (rg0 == colg)           e00 = 0.f;
                    if (rg0 == colg + 32)      e01 = 0.f;
                    if (rg0 + 32 == colg)      e10 = 0.f;
                    if (rg0 + 32 == colg + 32) e11 = 0.f;
                }
                ps0[r] = e00 + e01;
                ps1[r] = e10 + e11;
            }
#pragma unroll
            for (int r = 0; r < 16; ++r) {
#pragma unroll
                for (int m = 1; m < 32; m <<= 1) {
                    ps0[r] += __shfl_xor(ps0[r], m);
                    ps1[r] += __shfl_xor(ps1[r], m);
                }
            }
            if (rlo == 0) {
#pragma unroll
                for (int r = 0; r < 16; ++r) {
                    const int rg0 = row0b + (r & 3) + 8 * (r >> 2);
                    atomicAdd(&rowsum[rg0], ps0[r]);
                    atomicAdd(&rowsum[rg0 + 32], ps1[r]);
                }
            }
            acc00 = f32x16{}; acc01 = f32x16{};
            acc10 = f32x16{}; acc11 = f32x16{};
        }
        ct = nct; kt = nkt;
    }
}

// ---------------- final: loss = mean(M + log S_i - pos) ---------------------
__global__ void kfinal(const float* __restrict__ rowsum, const float* __restrict__ pos,
                       float* __restrict__ out) {
    __shared__ float red[8];
    const int tid = threadIdx.x;
    float s = 0.f;
    for (int i = tid; i < N2; i += 512) {
        const int p = (i < NPAIR) ? i : i - NPAIR;
        s += INV_T + __logf(rowsum[i]) - pos[p];
    }
#pragma unroll
    for (int off = 32; off; off >>= 1) s += __shfl_xor(s, off);
    if ((tid & 63) == 0) red[tid >> 6] = s;
    __syncthreads();
    if (tid == 0) {
        float t = 0.f;
#pragma unroll
        for (int w = 0; w < 8; ++w) t += red[w];
        out[0] = t / (float)N2;
    }
}

extern "C" void kernel_launch(void* const* d_in, const int* in_sizes, int n_in,
                              void* d_out, int out_size, void* d_ws, size_t ws_size,
                              hipStream_t stream) {
    const float* z1 = (const float*)d_in[0];
    const float* z2 = (const float*)d_in[1];
    unsigned short* zb = (unsigned short*)d_ws;                       // 8192*768 bf16
    float* rowsum = (float*)((char*)d_ws + (size_t)N2 * DIM * 2);     // 8192 f32
    float* pos = rowsum + N2;                                         // 4096 f32
    float* out = (float*)d_out;

    hipLaunchKernelGGL(knorm, dim3(N2 / 4), dim3(256), 0, stream, z1, z2, zb);
    hipLaunchKernelGGL(kpos, dim3(NPAIR / 4), dim3(256), 0, stream, zb, pos);
    hipMemsetAsync(rowsum, 0, N2 * sizeof(float), stream);
    hipLaunchKernelGGL(klse, dim3(NBI, NSTRIP), dim3(256), 0, stream, zb, rowsum);
    hipLaunchKernelGGL(kfinal, dim3(1), dim3(512), 0, stream, rowsum, pos, out);
}

// Round 9
// 139.512 us; speedup vs baseline: 1.7009x; 1.7009x over previous
//
#include <hip/hip_runtime.h>
#include <hip/hip_bf16.h>

#define NPAIR 4096
#define DIM   768            // elements per row; 768 BYTES per row in fp8
#define N2    8192
#define BM    128            // block rows (4 waves as 2x2, each 64x64)
#define BNB   128            // block cols per col-block
#define KBLK  128            // K tile in fp8 bytes -> A,B tiles 16KB each
#define KITER (DIM / KBLK)   // 6
#define NSTRIP 16            // grid.y
#define CPB   ((N2 / BNB) / NSTRIP)    // 4 col-blocks per strip
#define NBI   (N2 / BM)      // 64

constexpr float INV_T = 1.0f / 0.07f;  // also the fixed softmax max M

typedef float f32x16 __attribute__((ext_vector_type(16)));

// ---------------- normalize: one wave per row, fp32 in -> fp8 e4m3 out ------
__global__ void knorm(const float* __restrict__ z1, const float* __restrict__ z2,
                      unsigned char* __restrict__ zq) {
    const int row  = blockIdx.x * 4 + (threadIdx.x >> 6);
    const int lane = threadIdx.x & 63;
    const float* src = (row < NPAIR) ? (z1 + (size_t)row * DIM)
                                     : (z2 + (size_t)(row - NPAIR) * DIM);
    float4 v[3];
    float ss = 0.f;
#pragma unroll
    for (int i = 0; i < 3; ++i) {
        v[i] = reinterpret_cast<const float4*>(src)[lane + 64 * i];
        ss += v[i].x * v[i].x + v[i].y * v[i].y + v[i].z * v[i].z + v[i].w * v[i].w;
    }
#pragma unroll
    for (int off = 32; off; off >>= 1) ss += __shfl_xor(ss, off);
    const float scale = 1.0f / fmaxf(sqrtf(ss), 1e-12f);
    unsigned int* dst = reinterpret_cast<unsigned int*>(zq + (size_t)row * DIM);
#pragma unroll
    for (int i = 0; i < 3; ++i) {
        unsigned int u = 0;
        u = __builtin_amdgcn_cvt_pk_fp8_f32(v[i].x * scale, v[i].y * scale, u, false);
        u = __builtin_amdgcn_cvt_pk_fp8_f32(v[i].z * scale, v[i].w * scale, u, true);
        dst[lane + 64 * i] = u;
    }
}

// ---------------- positive-pair dots from fp8 (consistent with klse) --------
__global__ void kpos(const unsigned char* __restrict__ zq, float* __restrict__ pos) {
    const int pair = blockIdx.x * 4 + (threadIdx.x >> 6);
    const int lane = threadIdx.x & 63;
    const unsigned int* a = reinterpret_cast<const unsigned int*>(zq + (size_t)pair * DIM);
    const unsigned int* b = reinterpret_cast<const unsigned int*>(zq + (size_t)(pair + NPAIR) * DIM);
    float s = 0.f;
#pragma unroll
    for (int i = 0; i < 3; ++i) {
        const unsigned int ua = a[lane + 64 * i];
        const unsigned int ub = b[lane + 64 * i];
        s += __builtin_amdgcn_cvt_f32_fp8(ua, 0) * __builtin_amdgcn_cvt_f32_fp8(ub, 0);
        s += __builtin_amdgcn_cvt_f32_fp8(ua, 1) * __builtin_amdgcn_cvt_f32_fp8(ub, 1);
        s += __builtin_amdgcn_cvt_f32_fp8(ua, 2) * __builtin_amdgcn_cvt_f32_fp8(ub, 2);
        s += __builtin_amdgcn_cvt_f32_fp8(ua, 3) * __builtin_amdgcn_cvt_f32_fp8(ub, 3);
    }
#pragma unroll
    for (int off = 32; off; off >>= 1) s += __shfl_xor(s, off);
    if (lane == 0) pos[pair] = s * INV_T;
}

// ---------------- main: full sweep, fp8 MFMA, R3 single-buffer engine -------
// 128x128 block, wave 64x64 via 2x2 of mfma_f32_32x32x16_fp8_fp8. A/B K-tiles
// (128 fp8 elems) single-buffered in 32KB LDS, staged by global_load_lds with
// XOR-swizzled source (granule slot ^ row&7); ds_read_b64 fragments are
// bank-optimal (4 words/bank = 512B minimum). Same grid/epilogue as R3.
__global__ __launch_bounds__(256) void klse(const unsigned char* __restrict__ zq,
                                            float* __restrict__ rowsum) {
    __shared__ __align__(16) unsigned char As[BM * KBLK];   // 16 KB
    __shared__ __align__(16) unsigned char Bs[BM * KBLK];   // 16 KB
    const int tid  = threadIdx.x;
    const int wave = tid >> 6;
    const int lane = tid & 63;
    const int wr = wave >> 1, wc = wave & 1;
    const int hi = lane >> 5, rlo = lane & 31;
    const int bi = blockIdx.x;
    const int rb = bi * BM;

    const int sw   = rlo & 7;                    // read-side granule swizzle
    const int raA  = (wr * 64 + rlo) * KBLK;     // A sub 0 row base (bytes)
    const int raB  = raA + 32 * KBLK;            // A sub 1
    const int caA  = (wc * 64 + rlo) * KBLK;     // B sub 0 col base
    const int caB  = caA + 32 * KBLK;            // B sub 1

    for (int ct = 0; ct < CPB; ++ct) {
        const int cblk = blockIdx.y * CPB + ct;
        const int c0 = cblk * BNB;

        f32x16 acc00 = {}, acc01 = {}, acc10 = {}, acc11 = {};

        for (int kt = 0; kt < KITER; ++kt) {
            __syncthreads();   // previous tile's reads complete before overwrite
#pragma unroll
            for (int i = 0; i < 4; ++i) {
                const int g = i * 256 + tid;       // 16B granule in [0,1024)
                const int r = g >> 3, slot = g & 7;
                const int ksrc = kt * KBLK + ((slot ^ (r & 7)) << 4);
                const unsigned char* srcA = zq + (size_t)(rb + r) * DIM + ksrc;
                const unsigned char* srcB = zq + (size_t)(c0 + r) * DIM + ksrc;
                __builtin_amdgcn_global_load_lds(
                    (const __attribute__((address_space(1))) unsigned int*)srcA,
                    (__attribute__((address_space(3))) unsigned int*)(As + g * 16),
                    16, 0, 0);
                __builtin_amdgcn_global_load_lds(
                    (const __attribute__((address_space(1))) unsigned int*)srcB,
                    (__attribute__((address_space(3))) unsigned int*)(Bs + g * 16),
                    16, 0, 0);
            }
            __syncthreads();

#pragma unroll
            for (int tt = 0; tt < 8; ++tt) {
                const int so = ((tt ^ sw) << 4) + (hi << 3);  // swizzled 8B offset
                long a0 = *reinterpret_cast<const long*>(&As[raA + so]);
                long a1 = *reinterpret_cast<const long*>(&As[raB + so]);
                long b0 = *reinterpret_cast<const long*>(&Bs[caA + so]);
                long b1 = *reinterpret_cast<const long*>(&Bs[caB + so]);
                acc00 = __builtin_amdgcn_mfma_f32_32x32x16_fp8_fp8(a0, b0, acc00, 0, 0, 0);
                acc01 = __builtin_amdgcn_mfma_f32_32x32x16_fp8_fp8(a0, b1, acc01, 0, 0, 0);
                acc10 = __builtin_amdgcn_mfma_f32_32x32x16_fp8_fp8(a1, b0, acc10, 0, 0, 0);
                acc11 = __builtin_amdgcn_mfma_f32_32x32x16_fp8_fp8(a1, b1, acc11, 0, 0, 0);
            }
        }

        // epilogue: exp, diagonal mask, row-sum reduce, atomic flush
        const bool on_diag = (cblk == bi);
        const int row0b = rb + wr * 64 + 4 * hi;
        const int colg  = c0 + wc * 64 + rlo;
        float ps0[16], ps1[16];
#pragma unroll
        for (int r = 0; r < 16; ++r) {
            const int rg0 = row0b + (r & 3) + 8 * (r >> 2);
            float e00 = __expf((acc00[r] - 1.0f) * INV_T);
            float e01 = __expf((acc01[r] - 1.0f) * INV_T);
            float e10 = __expf((acc10[r] - 1.0f) * INV_T);
            float e11 = __expf((acc11[r] - 1.0f) * INV_T);
            if (on_diag) {
                if (rg0 == colg)           e00 = 0.f;
                if (rg0 == colg + 32)      e01 = 0.f;
                if (rg0 + 32 == colg)      e10 = 0.f;
                if (rg0 + 32 == colg + 32) e11 = 0.f;
            }
            ps0[r] = e00 + e01;
            ps1[r] = e10 + e11;
        }
#pragma unroll
        for (int r = 0; r < 16; ++r) {
#pragma unroll
            for (int m = 1; m < 32; m <<= 1) {
                ps0[r] += __shfl_xor(ps0[r], m);
                ps1[r] += __shfl_xor(ps1[r], m);
            }
        }
        if (rlo == 0) {
#pragma unroll
            for (int r = 0; r < 16; ++r) {
                const int rg0 = row0b + (r & 3) + 8 * (r >> 2);
                atomicAdd(&rowsum[rg0], ps0[r]);
                atomicAdd(&rowsum[rg0 + 32], ps1[r]);
            }
        }
        __syncthreads();   // epilogue done before next ct re-stages
    }
}

// ---------------- final: loss = mean(M + log S_i - pos) ---------------------
__global__ void kfinal(const float* __restrict__ rowsum, const float* __restrict__ pos,
                       float* __restrict__ out) {
    __shared__ float red[8];
    const int tid = threadIdx.x;
    float s = 0.f;
    for (int i = tid; i < N2; i += 512) {
        const int p = (i < NPAIR) ? i : i - NPAIR;
        s += INV_T + __logf(rowsum[i]) - pos[p];
    }
#pragma unroll
    for (int off = 32; off; off >>= 1) s += __shfl_xor(s, off);
    if ((tid & 63) == 0) red[tid >> 6] = s;
    __syncthreads();
    if (tid == 0) {
        float t = 0.f;
#pragma unroll
        for (int w = 0; w < 8; ++w) t += red[w];
        out[0] = t / (float)N2;
    }
}

extern "C" void kernel_launch(void* const* d_in, const int* in_sizes, int n_in,
                              void* d_out, int out_size, void* d_ws, size_t ws_size,
                              hipStream_t stream) {
    const float* z1 = (const float*)d_in[0];
    const float* z2 = (const float*)d_in[1];
    unsigned char* zq = (unsigned char*)d_ws;                         // 8192*768 fp8
    float* rowsum = (float*)((char*)d_ws + (size_t)N2 * DIM);         // 8192 f32
    float* pos = rowsum + N2;                                         // 4096 f32
    float* out = (float*)d_out;

    hipLaunchKernelGGL(knorm, dim3(N2 / 4), dim3(256), 0, stream, z1, z2, zq);
    hipLaunchKernelGGL(kpos, dim3(NPAIR / 4), dim3(256), 0, stream, zq, pos);
    hipMemsetAsync(rowsum, 0, N2 * sizeof(float), stream);
    hipLaunchKernelGGL(klse, dim3(NBI, NSTRIP), dim3(256), 0, stream, zq, rowsum);
    hipLaunchKernelGGL(kfinal, dim3(1), dim3(512), 0, stream, rowsum, pos, out);
}